// Round 9
// baseline (269.733 us; speedup 1.0000x reference)
//
#include <hip/hip_runtime.h>
#include <hip/hip_bf16.h>
#include <cmath>

#define NT 256
#define HID 128

typedef __attribute__((ext_vector_type(8))) short short8v;   // 8 bf16 = 4 VGPR
typedef __attribute__((ext_vector_type(4))) float f32x4;

__device__ __forceinline__ unsigned short f2bf(float f) {
    __hip_bfloat16 h(f);
    return __builtin_bit_cast(unsigned short, h);
}
__device__ __forceinline__ float bf_lo(unsigned int u) { return __uint_as_float(u << 16); }
__device__ __forceinline__ float bf_hi(unsigned int u) { return __uint_as_float(u & 0xffff0000u); }

// cheap round-half-up bf16 pack (inputs finite)
__device__ __forceinline__ unsigned pk(float lo, float hi) {
    unsigned ul = __float_as_uint(lo), uh = __float_as_uint(hi);
    return ((ul + 0x8000u) >> 16) | ((uh + 0x8000u) & 0xffff0000u);
}
__device__ __forceinline__ unsigned short bf1(float v) {
    return (unsigned short)((__float_as_uint(v) + 0x8000u) >> 16);
}

__device__ __forceinline__ float fast_tanh(float x) {
    float cx = fminf(fmaxf(x, -15.f), 15.f);
    float e = __expf(2.f * cx);
    return (e - 1.f) / (e + 1.f);
}

#define MFMA16(a, b, c) __builtin_amdgcn_mfma_f32_16x16x32_bf16(a, b, c, 0, 0, 0)

// ---------------- setup kernels ----------------

// cnt init = 1: self-loop is part of the CSR row
__global__ void k_zero(int* __restrict__ cnt, int* __restrict__ order, int N) {
    int i = blockIdx.x * blockDim.x + threadIdx.x;
    order[i] = -1;
    if (i < N) cnt[i] = 1;
}

__global__ void k_hist_edge(const int* __restrict__ dst, int* __restrict__ cnt, int E) {
    int e = blockIdx.x * blockDim.x + threadIdx.x;
    if (e < E) atomicAdd(&cnt[dst[e]], 1);
}

// per-block type histogram -> blkT[t][b]  (no global atomics)
__global__ void k_hist_type(const int* __restrict__ type, int* __restrict__ blkT,
                            int nb2, int N) {
    __shared__ int h[4];
    int tid = threadIdx.x;
    if (tid < 4) h[tid] = 0;
    __syncthreads();
    int i = blockIdx.x * NT + tid;
    int t = (i < N) ? type[i] : -1;
    int lane = tid & 63;
    #pragma unroll
    for (int tt = 0; tt < 4; ++tt) {
        unsigned long long m = __ballot(t == tt);
        if (lane == 0 && m) atomicAdd(&h[tt], __popcll(m));   // LDS atomic only
    }
    __syncthreads();
    if (tid < 4) blkT[tid * nb2 + blockIdx.x] = h[tid];
}

// block-sum of 1024 cnt entries -> partials[block]
__global__ void k_scan1(const int* __restrict__ cnt, int* __restrict__ partials, int N) {
    __shared__ int sdata[NT];
    int base = blockIdx.x * 1024;
    int tid = threadIdx.x;
    int s = 0;
    #pragma unroll
    for (int k = 0; k < 4; ++k) {
        int idx = base + tid * 4 + k;
        if (idx < N) s += cnt[idx];
    }
    sdata[tid] = s;
    __syncthreads();
    for (int off = NT / 2; off > 0; off >>= 1) {
        if (tid < off) sdata[tid] += sdata[tid + off];
        __syncthreads();
    }
    if (tid == 0) partials[blockIdx.x] = sdata[0];
}

// one block: parallel scan of partials (nb<=512) AND per-type scans of blkT (nb2<=512)
__global__ void k_scanmeta(int* __restrict__ partials, int nb,
                           const int* __restrict__ blkT, int* __restrict__ blkBase,
                           int nb2, int* __restrict__ rowptr, int N) {
    __shared__ int s[NT];
    __shared__ int carry;
    int tid = threadIdx.x;

    int v0 = (tid * 2 < nb) ? partials[tid * 2] : 0;
    int v1 = (tid * 2 + 1 < nb) ? partials[tid * 2 + 1] : 0;
    int ts = v0 + v1;
    s[tid] = ts;
    __syncthreads();
    for (int off = 1; off < NT; off <<= 1) {
        int x = (tid >= off) ? s[tid - off] : 0;
        __syncthreads();
        s[tid] += x;
        __syncthreads();
    }
    int excl = s[tid] - ts;
    if (tid * 2 < nb) partials[tid * 2] = excl;
    if (tid * 2 + 1 < nb) partials[tid * 2 + 1] = excl + v0;
    if (tid == NT - 1) rowptr[N] = s[NT - 1];
    __syncthreads();

    if (tid == 0) carry = 0;
    __syncthreads();
    for (int t = 0; t < 4; ++t) {
        int w0 = (tid * 2 < nb2) ? blkT[t * nb2 + tid * 2] : 0;
        int w1 = (tid * 2 + 1 < nb2) ? blkT[t * nb2 + tid * 2 + 1] : 0;
        int tw = w0 + w1;
        s[tid] = tw;
        __syncthreads();
        for (int off = 1; off < NT; off <<= 1) {
            int x = (tid >= off) ? s[tid - off] : 0;
            __syncthreads();
            s[tid] += x;
            __syncthreads();
        }
        int ex = s[tid] - tw;
        int base = carry;
        if (tid * 2 < nb2) blkBase[t * nb2 + tid * 2] = base + ex;
        if (tid * 2 + 1 < nb2) blkBase[t * nb2 + tid * 2 + 1] = base + ex + w0;
        __syncthreads();
        if (tid == NT - 1) carry = (base + s[NT - 1] + 255) & ~255;
        __syncthreads();
    }
}

// block-local exclusive scan + prefix -> rowptr/cursor/dinv; writes self-loop edge
__global__ void k_scan3(const int* __restrict__ cnt, const int* __restrict__ partials,
                        int* __restrict__ rowptr, int* __restrict__ cursor,
                        float* __restrict__ dinv, int* __restrict__ col, int N) {
    __shared__ int sdata[NT];
    int base = blockIdx.x * 1024;
    int tid = threadIdx.x;
    int a[4];
    int s = 0;
    #pragma unroll
    for (int k = 0; k < 4; ++k) {
        int idx = base + tid * 4 + k;
        a[k] = (idx < N) ? cnt[idx] : 0;
        s += a[k];
    }
    sdata[tid] = s;
    __syncthreads();
    for (int off = 1; off < NT; off <<= 1) {
        int v = (tid >= off) ? sdata[tid - off] : 0;
        __syncthreads();
        sdata[tid] += v;
        __syncthreads();
    }
    int excl = sdata[tid] - s;
    int run = partials[blockIdx.x] + excl;
    #pragma unroll
    for (int k = 0; k < 4; ++k) {
        int idx = base + tid * 4 + k;
        if (idx < N) {
            rowptr[idx] = run;
            col[run] = idx;            // self-loop first in row
            cursor[idx] = run + 1;     // appended edges go after it
            dinv[idx] = rsqrtf((float)a[k]);   // cnt includes self
            run += a[k];
        }
    }
}

// deterministic, atomic-free type-bucketing scatter
__global__ void k_scatter(const int* __restrict__ type, const int* __restrict__ blkBase,
                          int nb2, int* __restrict__ order, int N) {
    __shared__ int wcnt[4][4];   // [wave][type]
    int tid = threadIdx.x, lane = tid & 63, w = tid >> 6;
    int i = blockIdx.x * NT + tid;
    int t = (i < N) ? type[i] : -1;
    unsigned long long below = (1ull << lane) - 1ull;
    unsigned long long mym = 0;
    #pragma unroll
    for (int tt = 0; tt < 4; ++tt) {
        unsigned long long m = __ballot(t == tt);
        if (lane == 0) wcnt[w][tt] = __popcll(m);
        if (t == tt) mym = m;
    }
    __syncthreads();
    if (t >= 0) {
        int off = 0;
        #pragma unroll
        for (int w2 = 0; w2 < 4; ++w2)
            if (w2 < w) off += wcnt[w2][t];
        int pos = blkBase[t * nb2 + blockIdx.x] + off + __popcll(mym & below);
        order[pos] = i;
    }
}

__global__ void k_fill(const int* __restrict__ src, const int* __restrict__ dst,
                       int* __restrict__ cursor, int* __restrict__ col, int E) {
    int e = blockIdx.x * blockDim.x + threadIdx.x;
    if (e < E) {
        int p = atomicAdd(&cursor[dst[e]], 1);
        col[p] = src[e];
    }
}

// convert + transpose weights to bf16: Wt[col][k] = W[k][col]
__global__ void k_prep(const float* __restrict__ AW, const float* __restrict__ W1,
                       const float* __restrict__ W2, unsigned short* __restrict__ AWt,
                       unsigned short* __restrict__ W1t, unsigned short* __restrict__ W2t) {
    int i = blockIdx.x * NT + threadIdx.x;
    if (i < 65536) {
        int t = i >> 14, rem = i & 16383, c = rem >> 7, k = rem & 127;
        AWt[i] = f2bf(AW[t * 16384 + k * 128 + c]);
    } else if (i < 81920) {
        int j = i - 65536, c = j >> 7, k = j & 127;
        W1t[j] = f2bf(W1[k * 128 + c]);
    } else if (i < 98304) {
        int j = i - 81920, c = j >> 7, k = j & 127;
        W2t[j] = f2bf(W2[k * 128 + c]);
    }
}

// ---------------- main kernels ----------------
// 64-row blocks, 4 waves x 16 rows.
// mfma_f32_16x16x32_bf16 (m89 layouts): A lane: A[lane&15][8*(lane>>4)+j];
// B lane: B[8*(lane>>4)+j][lane&15]; D: col=lane&15, row=4*(lane>>4)+reg.

// A0d[n] = bf16( tanh(X[n]@AW[t] + Ab[t]) * dinv[n] ); W staged in LDS (type-specific
// W matrices thrash L1 when multiple types share a CU).
__global__ __launch_bounds__(NT) void k_adapt(const float* __restrict__ X,
                                              const int* __restrict__ type,
                                              const int* __restrict__ order,
                                              const unsigned short* __restrict__ AWt,
                                              const float* __restrict__ Ab,
                                              const float* __restrict__ dinv,
                                              unsigned short* __restrict__ A0d) {
    __shared__ unsigned short lds[24576];   // 48 KB: 32 KB W + 16 KB tile
    char* ldsb = (char*)lds;
    char* Tb = ldsb + 32768;
    const int i0 = blockIdx.x * 64;
    int n0 = order[i0];
    if (n0 < 0) return;                     // all-padding block
    const int tid = threadIdx.x;
    const int lane = tid & 63;
    const int w = tid >> 6;
    const int r = lane & 15, g = lane >> 4;
    const int t = __builtin_amdgcn_readfirstlane(type[n0]);
    const unsigned short* Wt = AWt + t * 16384;

    {   // stage W -> LDS (swizzled)
        int row = tid >> 1, half = tid & 1;
        const uint4* src = (const uint4*)(Wt + row * 128 + half * 64);
        #pragma unroll
        for (int j = 0; j < 8; ++j) {
            int gr = half * 8 + j;
            *(uint4*)(ldsb + row * 256 + ((gr ^ (row & 15)) << 4)) = src[j];
        }
    }

    int oid = order[i0 + w * 16 + r];
    float dvl = (oid >= 0) ? dinv[oid] : 0.f;

    float4 xv[8];
    if (oid >= 0) {
        const float4* xp = (const float4*)(X + (size_t)oid * 128);
        #pragma unroll
        for (int s = 0; s < 4; ++s) {
            xv[2 * s] = xp[s * 8 + g * 2];
            xv[2 * s + 1] = xp[s * 8 + g * 2 + 1];
        }
    } else {
        #pragma unroll
        for (int k = 0; k < 8; ++k) xv[k] = float4{0.f, 0.f, 0.f, 0.f};
    }

    float bcol[8];
    #pragma unroll
    for (int c = 0; c < 8; ++c) bcol[c] = Ab[t * 128 + c * 16 + r];

    f32x4 acc[8];
    #pragma unroll
    for (int c = 0; c < 8; ++c) { acc[c][0] = 0.f; acc[c][1] = 0.f; acc[c][2] = 0.f; acc[c][3] = 0.f; }

    __syncthreads();   // W ready

    #pragma unroll
    for (int s = 0; s < 4; ++s) {
        union { short8v s8; unsigned u[4]; } a;
        a.u[0] = pk(xv[2 * s].x, xv[2 * s].y);
        a.u[1] = pk(xv[2 * s].z, xv[2 * s].w);
        a.u[2] = pk(xv[2 * s + 1].x, xv[2 * s + 1].y);
        a.u[3] = pk(xv[2 * s + 1].z, xv[2 * s + 1].w);
        int slot = s * 4 + g;
        #pragma unroll
        for (int c = 0; c < 8; ++c) {
            int wr = 16 * c + r;
            short8v b = *(const short8v*)(ldsb + wr * 256 + ((slot ^ (wr & 15)) << 4));
            acc[c] = MFMA16(a.s8, b, acc[c]);
        }
    }

    float dn[4];
    #pragma unroll
    for (int q = 0; q < 4; ++q) dn[q] = __shfl(dvl, 4 * g + q);
    #pragma unroll
    for (int c = 0; c < 8; ++c) {
        #pragma unroll
        for (int q = 0; q < 4; ++q) {
            int row = w * 16 + 4 * g + q;
            int cb = (c * 16 + r) * 2;
            float v = fast_tanh(acc[c][q] + bcol[c]) * dn[q];
            *(unsigned short*)(Tb + row * 256 + (((cb >> 4) ^ (row & 15)) << 4) + (cb & 15)) = bf1(v);
        }
    }
    // stores: wave-local rows
    int row = tid >> 2;
    int d = order[i0 + row];
    if (d >= 0) {
        unsigned short* dst = A0d + (size_t)d * 128;
        #pragma unroll
        for (int k = 0; k < 4; ++k) {
            int gr = (tid & 3) * 4 + k;
            uint4 v = *(const uint4*)(Tb + row * 256 + ((gr ^ (row & 15)) << 4));
            *(uint4*)(dst + gr * 8) = v;
        }
    }
}

// Fused gather-sum + GEMM, scalarized edge walk (no shuffles/bpermute).
// S[d] = dinv[d] * sum_{e in row d} Yin[col[e]]  (self-loop in CSR)
// OUTF32=false: out_bf16[d] = (S@W + bias)*dinv[d];  OUTF32=true: out_f32[d] = S@W + bias.
template <bool OUTF32>
__global__ __launch_bounds__(NT) void k_layer(const unsigned short* __restrict__ Yin,
                                              const int* __restrict__ rowptr,
                                              const int* __restrict__ col,
                                              const float* __restrict__ dinv,
                                              const unsigned short* __restrict__ Wt,
                                              const float* __restrict__ bias,
                                              void* __restrict__ outp, int N) {
    __shared__ unsigned short lds[8192];    // 16 KB S tile
    char* Tb = (char*)lds;
    const int tid = threadIdx.x;
    const int lane = tid & 63;
    const int w = tid >> 6;
    const int r = lane & 15, g = lane >> 4;

    const int nbase = blockIdx.x * 64 + w * 16;
    const unsigned* Yw = (const unsigned*)Yin;

    // scalar per-node edge ranges (SGPR-resident via readfirstlane)
    int p[16], len[16];
    int ml = 0;
    #pragma unroll
    for (int j = 0; j < 16; ++j) {
        int d = nbase + j;
        int b = __builtin_amdgcn_readfirstlane(rowptr[d < N ? d : N]);
        int e2 = __builtin_amdgcn_readfirstlane(rowptr[d < N ? d + 1 : N]);
        p[j] = b;
        len[j] = e2 - b;                 // 0 when d >= N
        ml = ml > len[j] ? ml : len[j];
    }
    const int p0 = p[0];                 // valid self-loop edge when wave has work

    float ax[16], ay[16];
    #pragma unroll
    for (int j = 0; j < 16; ++j) { ax[j] = 0.f; ay[j] = 0.f; }

    // lock-step edge walk: per step, 16 scalar col reads + 16 independent row gathers
    for (int step = 0; step < ml; ++step) {
        unsigned v[16];
        float wt[16];
        #pragma unroll
        for (int j = 0; j < 16; ++j) {
            bool act = step < len[j];                 // wave-uniform
            int cidx = act ? p[j] + step : p0;        // scalar select
            int s = col[cidx];                        // uniform -> scalar load
            v[j] = Yw[(size_t)s * 64 + lane];         // 256B coalesced row gather
            wt[j] = act ? 1.f : 0.f;
        }
        #pragma unroll
        for (int j = 0; j < 16; ++j) {
            ax[j] = fmaf(wt[j], bf_lo(v[j]), ax[j]);
            ay[j] = fmaf(wt[j], bf_hi(v[j]), ay[j]);
        }
    }

    // write S rows (wave-local tile region), pre-scaled by dinv[d]
    #pragma unroll
    for (int j = 0; j < 16; ++j) {
        int d = nbase + j;
        if (d < N) {                                  // uniform branch
            float dn = dinv[d];                       // uniform
            unsigned pv = pk(ax[j] * dn, ay[j] * dn);
            int row = w * 16 + j;
            *(unsigned*)(Tb + row * 256 + (((lane >> 2) ^ (row & 15)) << 4) + (lane & 3) * 4) = pv;
        }
    }

    __syncthreads();
    __builtin_amdgcn_sched_barrier(0);   // keep B-loads out of the gather phase

    float bcol[8];
    #pragma unroll
    for (int c = 0; c < 8; ++c) bcol[c] = bias[c * 16 + r];

    f32x4 acc[8];
    #pragma unroll
    for (int c = 0; c < 8; ++c) { acc[c][0] = 0.f; acc[c][1] = 0.f; acc[c][2] = 0.f; acc[c][3] = 0.f; }

    const int arow = w * 16 + r;   // arow & 15 == r
    #pragma unroll
    for (int s = 0; s < 4; ++s) {
        int slot = s * 4 + g;
        short8v a = *(const short8v*)(Tb + arow * 256 + ((slot ^ r) << 4));
        #pragma unroll
        for (int c = 0; c < 8; ++c) {
            int wr = 16 * c + r;
            short8v b = *(const short8v*)(Wt + wr * 128 + slot * 8);   // global, L1-hot (shared W)
            acc[c] = MFMA16(a, b, acc[c]);
        }
    }

    if (OUTF32) {
        // direct f32 stores: per (c,q) each 16-lane group writes a full 64B segment
        #pragma unroll
        for (int c = 0; c < 8; ++c) {
            #pragma unroll
            for (int q = 0; q < 4; ++q) {
                int d = nbase + 4 * g + q;
                if (d < N)
                    ((float*)outp)[(size_t)d * 128 + c * 16 + r] = acc[c][q] + bcol[c];
            }
        }
    } else {
        #pragma unroll
        for (int c = 0; c < 8; ++c) {
            #pragma unroll
            for (int q = 0; q < 4; ++q) {
                int dd = nbase + 4 * g + q;
                float dnq = (dd < N) ? dinv[dd] : 0.f;
                int row = w * 16 + 4 * g + q;
                int cb = (c * 16 + r) * 2;
                float v = (acc[c][q] + bcol[c]) * dnq;
                *(unsigned short*)(Tb + row * 256 + (((cb >> 4) ^ (row & 15)) << 4) + (cb & 15)) = bf1(v);
            }
        }
        int row = tid >> 2;           // wave-local rows
        int d = blockIdx.x * 64 + row;
        if (d < N) {
            unsigned short* dst = (unsigned short*)outp + (size_t)d * 128;
            #pragma unroll
            for (int k = 0; k < 4; ++k) {
                int gr = (tid & 3) * 4 + k;
                uint4 v = *(const uint4*)(Tb + row * 256 + ((gr ^ (row & 15)) << 4));
                *(uint4*)(dst + gr * 8) = v;
            }
        }
    }
}

// ---------------- launch ----------------

extern "C" void kernel_launch(void* const* d_in, const int* in_sizes, int n_in,
                              void* d_out, int out_size, void* d_ws, size_t ws_size,
                              hipStream_t stream) {
    const float* X = (const float*)d_in[0];
    const int* ntype = (const int*)d_in[1];
    const int* eidx = (const int*)d_in[3];
    const float* AW = (const float*)d_in[5];
    const float* Ab = (const float*)d_in[6];
    const float* W1 = (const float*)d_in[7];
    const float* b1 = (const float*)d_in[8];
    const float* W2 = (const float*)d_in[9];
    const float* b2 = (const float*)d_in[10];

    int N = in_sizes[0] / HID;
    int E = in_sizes[3] / 2;
    const int* esrc = eidx;
    const int* edst = eidx + E;
    float* out = (float*)d_out;

    int gN = (N + NT - 1) / NT;      // also nb2 (<=512)
    int gE = (E + NT - 1) / NT;
    int gA = gN + 4;                 // padded bucket blocks (256-aligned starts)
    int Nord = gA * NT;
    int nb = (N + 1023) / 1024;      // <= 512

    char* ws = (char*)d_ws;
    size_t off = 0;
    auto carve = [&](size_t bytes) -> void* {
        void* p = ws + off;
        off += (bytes + 255) & ~(size_t)255;
        return p;
    };
    unsigned short* A0d = (unsigned short*)carve((size_t)N * HID * 2);  // bf16 adapt out (dinv-scaled)
    unsigned short* H1d = (unsigned short*)carve((size_t)N * HID * 2);  // bf16 layer1 out (dinv-scaled)
    unsigned short* AWt = (unsigned short*)carve(4 * 16384 * 2);
    unsigned short* W1t = (unsigned short*)carve(16384 * 2);
    unsigned short* W2t = (unsigned short*)carve(16384 * 2);
    int* cnt = (int*)carve((size_t)N * sizeof(int));
    int* rowptr = (int*)carve((size_t)(N + 1) * sizeof(int));
    int* cursor = (int*)carve((size_t)N * sizeof(int));
    float* dinv = (float*)carve((size_t)N * sizeof(float));
    int* order = (int*)carve((size_t)Nord * sizeof(int));
    int* col = (int*)carve((size_t)(E + N) * sizeof(int));   // self-loops included
    int* blkT = (int*)carve((size_t)4 * gN * sizeof(int));
    int* blkBase = (int*)carve((size_t)4 * gN * sizeof(int));
    int* partials = (int*)carve((size_t)nb * sizeof(int));
    (void)ws_size;
    (void)n_in;
    (void)out_size;

    k_zero<<<gA, NT, 0, stream>>>(cnt, order, N);
    k_hist_edge<<<gE, NT, 0, stream>>>(edst, cnt, E);
    k_hist_type<<<gN, NT, 0, stream>>>(ntype, blkT, gN, N);
    k_prep<<<384, NT, 0, stream>>>(AW, W1, W2, AWt, W1t, W2t);
    k_scan1<<<nb, NT, 0, stream>>>(cnt, partials, N);
    k_scanmeta<<<1, NT, 0, stream>>>(partials, nb, blkT, blkBase, gN, rowptr, N);
    k_scan3<<<nb, NT, 0, stream>>>(cnt, partials, rowptr, cursor, dinv, col, N);
    k_scatter<<<gN, NT, 0, stream>>>(ntype, blkBase, gN, order, N);
    k_fill<<<gE, NT, 0, stream>>>(esrc, edst, cursor, col, E);

    int bA = gA * 4;                 // 64-row blocks over order space
    int bL = (N + 63) / 64;

    k_adapt<<<bA, NT, 0, stream>>>(X, ntype, order, AWt, Ab, dinv, A0d);
    k_layer<false><<<bL, NT, 0, stream>>>(A0d, rowptr, col, dinv, W1t, b1, (void*)H1d, N);
    k_layer<true><<<bL, NT, 0, stream>>>(H1d, rowptr, col, dinv, W2t, b2, (void*)out, N);
}

// Round 10
// 266.220 us; speedup vs baseline: 1.0132x; 1.0132x over previous
//
#include <hip/hip_runtime.h>
#include <hip/hip_bf16.h>
#include <cmath>

#define NT 256
#define HID 128

typedef __attribute__((ext_vector_type(8))) short short8v;   // 8 bf16 = 4 VGPR
typedef __attribute__((ext_vector_type(4))) float f32x4;

__device__ __forceinline__ unsigned short f2bf(float f) {
    __hip_bfloat16 h(f);
    return __builtin_bit_cast(unsigned short, h);
}
__device__ __forceinline__ float bf_lo(unsigned int u) { return __uint_as_float(u << 16); }
__device__ __forceinline__ float bf_hi(unsigned int u) { return __uint_as_float(u & 0xffff0000u); }

// cheap round-half-up bf16 pack (inputs finite)
__device__ __forceinline__ unsigned pk(float lo, float hi) {
    unsigned ul = __float_as_uint(lo), uh = __float_as_uint(hi);
    return ((ul + 0x8000u) >> 16) | ((uh + 0x8000u) & 0xffff0000u);
}
__device__ __forceinline__ unsigned short bf1(float v) {
    return (unsigned short)((__float_as_uint(v) + 0x8000u) >> 16);
}

__device__ __forceinline__ float fast_tanh(float x) {
    float cx = fminf(fmaxf(x, -15.f), 15.f);
    float e = __expf(2.f * cx);
    return (e - 1.f) / (e + 1.f);
}

#define MFMA16(a, b, c) __builtin_amdgcn_mfma_f32_16x16x32_bf16(a, b, c, 0, 0, 0)

// ---------------- setup kernels ----------------

// cnt init = 1: self-loop is part of the CSR row
__global__ void k_zero(int* __restrict__ cnt, int* __restrict__ order, int N) {
    int i = blockIdx.x * blockDim.x + threadIdx.x;
    order[i] = -1;
    if (i < N) cnt[i] = 1;
}

__global__ void k_hist_edge(const int* __restrict__ dst, int* __restrict__ cnt, int E) {
    int e = blockIdx.x * blockDim.x + threadIdx.x;
    if (e < E) atomicAdd(&cnt[dst[e]], 1);
}

// per-block type histogram -> blkT[t][b]  (no global atomics)
__global__ void k_hist_type(const int* __restrict__ type, int* __restrict__ blkT,
                            int nb2, int N) {
    __shared__ int h[4];
    int tid = threadIdx.x;
    if (tid < 4) h[tid] = 0;
    __syncthreads();
    int i = blockIdx.x * NT + tid;
    int t = (i < N) ? type[i] : -1;
    int lane = tid & 63;
    #pragma unroll
    for (int tt = 0; tt < 4; ++tt) {
        unsigned long long m = __ballot(t == tt);
        if (lane == 0 && m) atomicAdd(&h[tt], __popcll(m));   // LDS atomic only
    }
    __syncthreads();
    if (tid < 4) blkT[tid * nb2 + blockIdx.x] = h[tid];
}

// block-sum of 1024 cnt entries -> partials[block]
__global__ void k_scan1(const int* __restrict__ cnt, int* __restrict__ partials, int N) {
    __shared__ int sdata[NT];
    int base = blockIdx.x * 1024;
    int tid = threadIdx.x;
    int s = 0;
    #pragma unroll
    for (int k = 0; k < 4; ++k) {
        int idx = base + tid * 4 + k;
        if (idx < N) s += cnt[idx];
    }
    sdata[tid] = s;
    __syncthreads();
    for (int off = NT / 2; off > 0; off >>= 1) {
        if (tid < off) sdata[tid] += sdata[tid + off];
        __syncthreads();
    }
    if (tid == 0) partials[blockIdx.x] = sdata[0];
}

// one block: parallel scan of partials (nb<=512) AND per-type scans of blkT (nb2<=512)
__global__ void k_scanmeta(int* __restrict__ partials, int nb,
                           const int* __restrict__ blkT, int* __restrict__ blkBase,
                           int nb2, int* __restrict__ rowptr, int N) {
    __shared__ int s[NT];
    __shared__ int carry;
    int tid = threadIdx.x;

    int v0 = (tid * 2 < nb) ? partials[tid * 2] : 0;
    int v1 = (tid * 2 + 1 < nb) ? partials[tid * 2 + 1] : 0;
    int ts = v0 + v1;
    s[tid] = ts;
    __syncthreads();
    for (int off = 1; off < NT; off <<= 1) {
        int x = (tid >= off) ? s[tid - off] : 0;
        __syncthreads();
        s[tid] += x;
        __syncthreads();
    }
    int excl = s[tid] - ts;
    if (tid * 2 < nb) partials[tid * 2] = excl;
    if (tid * 2 + 1 < nb) partials[tid * 2 + 1] = excl + v0;
    if (tid == NT - 1) rowptr[N] = s[NT - 1];
    __syncthreads();

    if (tid == 0) carry = 0;
    __syncthreads();
    for (int t = 0; t < 4; ++t) {
        int w0 = (tid * 2 < nb2) ? blkT[t * nb2 + tid * 2] : 0;
        int w1 = (tid * 2 + 1 < nb2) ? blkT[t * nb2 + tid * 2 + 1] : 0;
        int tw = w0 + w1;
        s[tid] = tw;
        __syncthreads();
        for (int off = 1; off < NT; off <<= 1) {
            int x = (tid >= off) ? s[tid - off] : 0;
            __syncthreads();
            s[tid] += x;
            __syncthreads();
        }
        int ex = s[tid] - tw;
        int base = carry;
        if (tid * 2 < nb2) blkBase[t * nb2 + tid * 2] = base + ex;
        if (tid * 2 + 1 < nb2) blkBase[t * nb2 + tid * 2 + 1] = base + ex + w0;
        __syncthreads();
        if (tid == NT - 1) carry = (base + s[NT - 1] + 255) & ~255;
        __syncthreads();
    }
}

// block-local exclusive scan + prefix -> rowptr/cursor/dinv; writes self-loop edge
__global__ void k_scan3(const int* __restrict__ cnt, const int* __restrict__ partials,
                        int* __restrict__ rowptr, int* __restrict__ cursor,
                        float* __restrict__ dinv, int* __restrict__ col, int N) {
    __shared__ int sdata[NT];
    int base = blockIdx.x * 1024;
    int tid = threadIdx.x;
    int a[4];
    int s = 0;
    #pragma unroll
    for (int k = 0; k < 4; ++k) {
        int idx = base + tid * 4 + k;
        a[k] = (idx < N) ? cnt[idx] : 0;
        s += a[k];
    }
    sdata[tid] = s;
    __syncthreads();
    for (int off = 1; off < NT; off <<= 1) {
        int v = (tid >= off) ? sdata[tid - off] : 0;
        __syncthreads();
        sdata[tid] += v;
        __syncthreads();
    }
    int excl = sdata[tid] - s;
    int run = partials[blockIdx.x] + excl;
    #pragma unroll
    for (int k = 0; k < 4; ++k) {
        int idx = base + tid * 4 + k;
        if (idx < N) {
            rowptr[idx] = run;
            col[run] = idx;            // self-loop first in row
            cursor[idx] = run + 1;     // appended edges go after it
            dinv[idx] = rsqrtf((float)a[k]);   // cnt includes self
            run += a[k];
        }
    }
}

// deterministic, atomic-free type-bucketing scatter
__global__ void k_scatter(const int* __restrict__ type, const int* __restrict__ blkBase,
                          int nb2, int* __restrict__ order, int N) {
    __shared__ int wcnt[4][4];   // [wave][type]
    int tid = threadIdx.x, lane = tid & 63, w = tid >> 6;
    int i = blockIdx.x * NT + tid;
    int t = (i < N) ? type[i] : -1;
    unsigned long long below = (1ull << lane) - 1ull;
    unsigned long long mym = 0;
    #pragma unroll
    for (int tt = 0; tt < 4; ++tt) {
        unsigned long long m = __ballot(t == tt);
        if (lane == 0) wcnt[w][tt] = __popcll(m);
        if (t == tt) mym = m;
    }
    __syncthreads();
    if (t >= 0) {
        int off = 0;
        #pragma unroll
        for (int w2 = 0; w2 < 4; ++w2)
            if (w2 < w) off += wcnt[w2][t];
        int pos = blkBase[t * nb2 + blockIdx.x] + off + __popcll(mym & below);
        order[pos] = i;
    }
}

__global__ void k_fill(const int* __restrict__ src, const int* __restrict__ dst,
                       int* __restrict__ cursor, int* __restrict__ col, int E) {
    int e = blockIdx.x * blockDim.x + threadIdx.x;
    if (e < E) {
        int p = atomicAdd(&cursor[dst[e]], 1);
        col[p] = src[e];
    }
}

// convert + transpose weights to bf16: Wt[col][k] = W[k][col]
__global__ void k_prep(const float* __restrict__ AW, const float* __restrict__ W1,
                       const float* __restrict__ W2, unsigned short* __restrict__ AWt,
                       unsigned short* __restrict__ W1t, unsigned short* __restrict__ W2t) {
    int i = blockIdx.x * NT + threadIdx.x;
    if (i < 65536) {
        int t = i >> 14, rem = i & 16383, c = rem >> 7, k = rem & 127;
        AWt[i] = f2bf(AW[t * 16384 + k * 128 + c]);
    } else if (i < 81920) {
        int j = i - 65536, c = j >> 7, k = j & 127;
        W1t[j] = f2bf(W1[k * 128 + c]);
    } else if (i < 98304) {
        int j = i - 81920, c = j >> 7, k = j & 127;
        W2t[j] = f2bf(W2[k * 128 + c]);
    }
}

// ---------------- main kernels ----------------
// mfma_f32_16x16x32_bf16 (m89 layouts): A lane: A[lane&15][8*(lane>>4)+j];
// B lane: B[8*(lane>>4)+j][lane&15]; D: col=lane&15, row=4*(lane>>4)+reg.

// A0d[n] = bf16( tanh(X[n]@AW[t] + Ab[t]) * dinv[n] ); 64-row blocks, W staged in LDS.
__global__ __launch_bounds__(NT) void k_adapt(const float* __restrict__ X,
                                              const int* __restrict__ type,
                                              const int* __restrict__ order,
                                              const unsigned short* __restrict__ AWt,
                                              const float* __restrict__ Ab,
                                              const float* __restrict__ dinv,
                                              unsigned short* __restrict__ A0d) {
    __shared__ unsigned short lds[24576];   // 48 KB: 32 KB W + 16 KB tile
    char* ldsb = (char*)lds;
    char* Tb = ldsb + 32768;
    const int i0 = blockIdx.x * 64;
    int n0 = order[i0];
    if (n0 < 0) return;                     // all-padding block
    const int tid = threadIdx.x;
    const int lane = tid & 63;
    const int w = tid >> 6;
    const int r = lane & 15, g = lane >> 4;
    const int t = __builtin_amdgcn_readfirstlane(type[n0]);
    const unsigned short* Wt = AWt + t * 16384;

    {   // stage W -> LDS (swizzled)
        int row = tid >> 1, half = tid & 1;
        const uint4* src = (const uint4*)(Wt + row * 128 + half * 64);
        #pragma unroll
        for (int j = 0; j < 8; ++j) {
            int gr = half * 8 + j;
            *(uint4*)(ldsb + row * 256 + ((gr ^ (row & 15)) << 4)) = src[j];
        }
    }

    int oid = order[i0 + w * 16 + r];
    float dvl = (oid >= 0) ? dinv[oid] : 0.f;

    float4 xv[8];
    if (oid >= 0) {
        const float4* xp = (const float4*)(X + (size_t)oid * 128);
        #pragma unroll
        for (int s = 0; s < 4; ++s) {
            xv[2 * s] = xp[s * 8 + g * 2];
            xv[2 * s + 1] = xp[s * 8 + g * 2 + 1];
        }
    } else {
        #pragma unroll
        for (int k = 0; k < 8; ++k) xv[k] = float4{0.f, 0.f, 0.f, 0.f};
    }

    float bcol[8];
    #pragma unroll
    for (int c = 0; c < 8; ++c) bcol[c] = Ab[t * 128 + c * 16 + r];

    f32x4 acc[8];
    #pragma unroll
    for (int c = 0; c < 8; ++c) { acc[c][0] = 0.f; acc[c][1] = 0.f; acc[c][2] = 0.f; acc[c][3] = 0.f; }

    __syncthreads();   // W ready

    #pragma unroll
    for (int s = 0; s < 4; ++s) {
        union { short8v s8; unsigned u[4]; } a;
        a.u[0] = pk(xv[2 * s].x, xv[2 * s].y);
        a.u[1] = pk(xv[2 * s].z, xv[2 * s].w);
        a.u[2] = pk(xv[2 * s + 1].x, xv[2 * s + 1].y);
        a.u[3] = pk(xv[2 * s + 1].z, xv[2 * s + 1].w);
        int slot = s * 4 + g;
        #pragma unroll
        for (int c = 0; c < 8; ++c) {
            int wr = 16 * c + r;
            short8v b = *(const short8v*)(ldsb + wr * 256 + ((slot ^ (wr & 15)) << 4));
            acc[c] = MFMA16(a.s8, b, acc[c]);
        }
    }

    float dn[4];
    #pragma unroll
    for (int q = 0; q < 4; ++q) dn[q] = __shfl(dvl, 4 * g + q);
    #pragma unroll
    for (int c = 0; c < 8; ++c) {
        #pragma unroll
        for (int q = 0; q < 4; ++q) {
            int row = w * 16 + 4 * g + q;
            int cb = (c * 16 + r) * 2;
            float v = fast_tanh(acc[c][q] + bcol[c]) * dn[q];
            *(unsigned short*)(Tb + row * 256 + (((cb >> 4) ^ (row & 15)) << 4) + (cb & 15)) = bf1(v);
        }
    }
    // stores: wave-local rows
    int row = tid >> 2;
    int d = order[i0 + row];
    if (d >= 0) {
        unsigned short* dst = A0d + (size_t)d * 128;
        #pragma unroll
        for (int k = 0; k < 4; ++k) {
            int gr = (tid & 3) * 4 + k;
            uint4 v = *(const uint4*)(Tb + row * 256 + ((gr ^ (row & 15)) << 4));
            *(uint4*)(dst + gr * 8) = v;
        }
    }
}

// Standalone gather-sum: S[d] = bf16( dinv[d] * sum_{e in row d} Yin[col[e]] )
// (self-loop is in the CSR). 1 wave per node, 8 row-gathers in flight.
__global__ __launch_bounds__(NT) void k_agg(const unsigned short* __restrict__ Yin,
                                            const int* __restrict__ rowptr,
                                            const int* __restrict__ col,
                                            const float* __restrict__ dinv,
                                            unsigned short* __restrict__ Sout, int N) {
    int gw = (int)((blockIdx.x * (unsigned)blockDim.x + threadIdx.x) >> 6);
    int lane = threadIdx.x & 63;
    if (gw >= N) return;
    const unsigned* Yw = (const unsigned*)Yin;
    int beg = rowptr[gw], end = rowptr[gw + 1];
    float ax = 0.f, ay = 0.f;
    for (int base = beg; base < end; base += 64) {
        int m = end - base;
        if (m > 64) m = 64;
        int ce = (lane < m) ? col[base + lane] : col[beg];   // pad = self row
        for (int k = 0; k < m; k += 8) {
            unsigned v[8];
            #pragma unroll
            for (int j = 0; j < 8; ++j) {
                int idx = (k + j < m) ? k + j : 0;
                int s = __shfl(ce, idx);
                v[j] = Yw[(size_t)s * 64 + lane];
            }
            #pragma unroll
            for (int j = 0; j < 8; ++j) {
                float wj = (k + j < m) ? 1.f : 0.f;
                ax = fmaf(wj, bf_lo(v[j]), ax);
                ay = fmaf(wj, bf_hi(v[j]), ay);
            }
        }
    }
    float dn = dinv[gw];
    ((unsigned*)Sout)[(size_t)gw * 64 + lane] = pk(ax * dn, ay * dn);
}

// Pure GEMM over node rows: 64-row blocks, no barriers, W read from global (L2-hot).
// OUTF32=false: out_bf16[d] = (S@W + bias)*dinv[d];  OUTF32=true: out_f32[d] = S@W + bias.
template <bool OUTF32>
__global__ __launch_bounds__(NT) void k_mm(const unsigned short* __restrict__ Ain,
                                           const unsigned short* __restrict__ Wt,
                                           const float* __restrict__ bias,
                                           const float* __restrict__ dinv,
                                           void* __restrict__ outp, int N) {
    __shared__ unsigned short lds[8192];    // 16 KB tile (bf16-out path only)
    char* Tb = (char*)lds;
    const int tid = threadIdx.x;
    const int lane = tid & 63;
    const int w = tid >> 6;
    const int r = lane & 15, g = lane >> 4;
    const int nbase = blockIdx.x * 64 + w * 16;

    int n = nbase + r;
    if (n >= N) n = N - 1;                  // clamp (stores guarded)
    const unsigned short* arow = Ain + (size_t)n * 128;

    float bcol[8];
    #pragma unroll
    for (int c = 0; c < 8; ++c) bcol[c] = bias[c * 16 + r];

    f32x4 acc[8];
    #pragma unroll
    for (int c = 0; c < 8; ++c) { acc[c][0] = 0.f; acc[c][1] = 0.f; acc[c][2] = 0.f; acc[c][3] = 0.f; }

    #pragma unroll
    for (int s = 0; s < 4; ++s) {
        short8v a = *(const short8v*)(arow + s * 32 + g * 8);   // 64B/row segments, coalesced
        int slot = s * 4 + g;
        #pragma unroll
        for (int c = 0; c < 8; ++c) {
            int wr = 16 * c + r;
            short8v b = *(const short8v*)(Wt + wr * 128 + slot * 8);   // global, shared W
            acc[c] = MFMA16(a, b, acc[c]);
        }
    }

    if (OUTF32) {
        // direct f32 stores: per (c,q) each 16-lane group writes a 64B segment
        #pragma unroll
        for (int c = 0; c < 8; ++c) {
            #pragma unroll
            for (int q = 0; q < 4; ++q) {
                int d = nbase + 4 * g + q;
                if (d < N)
                    ((float*)outp)[(size_t)d * 128 + c * 16 + r] = acc[c][q] + bcol[c];
            }
        }
    } else {
        float dnq[4];
        #pragma unroll
        for (int q = 0; q < 4; ++q) {
            int dd = nbase + 4 * g + q;
            dnq[q] = (dd < N) ? dinv[dd] : 0.f;
        }
        #pragma unroll
        for (int c = 0; c < 8; ++c) {
            #pragma unroll
            for (int q = 0; q < 4; ++q) {
                int row = w * 16 + 4 * g + q;
                int cb = (c * 16 + r) * 2;
                float v = (acc[c][q] + bcol[c]) * dnq[q];
                *(unsigned short*)(Tb + row * 256 + (((cb >> 4) ^ (row & 15)) << 4) + (cb & 15)) = bf1(v);
            }
        }
        // tile rows are wave-local (tid>>2 in [w*16, w*16+16)) -> no barrier needed
        int row = tid >> 2;
        int d = blockIdx.x * 64 + row;
        if (d < N) {
            unsigned short* dst = (unsigned short*)outp + (size_t)d * 128;
            #pragma unroll
            for (int k = 0; k < 4; ++k) {
                int gr = (tid & 3) * 4 + k;
                uint4 v = *(const uint4*)(Tb + row * 256 + ((gr ^ (row & 15)) << 4));
                *(uint4*)(dst + gr * 8) = v;
            }
        }
    }
}

// ---------------- launch ----------------

extern "C" void kernel_launch(void* const* d_in, const int* in_sizes, int n_in,
                              void* d_out, int out_size, void* d_ws, size_t ws_size,
                              hipStream_t stream) {
    const float* X = (const float*)d_in[0];
    const int* ntype = (const int*)d_in[1];
    const int* eidx = (const int*)d_in[3];
    const float* AW = (const float*)d_in[5];
    const float* Ab = (const float*)d_in[6];
    const float* W1 = (const float*)d_in[7];
    const float* b1 = (const float*)d_in[8];
    const float* W2 = (const float*)d_in[9];
    const float* b2 = (const float*)d_in[10];

    int N = in_sizes[0] / HID;
    int E = in_sizes[3] / 2;
    const int* esrc = eidx;
    const int* edst = eidx + E;
    float* out = (float*)d_out;

    int gN = (N + NT - 1) / NT;      // also nb2 (<=512)
    int gE = (E + NT - 1) / NT;
    int gA = gN + 4;                 // padded bucket blocks (256-aligned starts)
    int Nord = gA * NT;
    int nb = (N + 1023) / 1024;      // <= 512

    char* ws = (char*)d_ws;
    size_t off = 0;
    auto carve = [&](size_t bytes) -> void* {
        void* p = ws + off;
        off += (bytes + 255) & ~(size_t)255;
        return p;
    };
    unsigned short* A0d = (unsigned short*)carve((size_t)N * HID * 2);  // adapt out / mm1 out (aliased)
    unsigned short* Sb = (unsigned short*)carve((size_t)N * HID * 2);   // agg out
    unsigned short* AWt = (unsigned short*)carve(4 * 16384 * 2);
    unsigned short* W1t = (unsigned short*)carve(16384 * 2);
    unsigned short* W2t = (unsigned short*)carve(16384 * 2);
    int* cnt = (int*)carve((size_t)N * sizeof(int));
    int* rowptr = (int*)carve((size_t)(N + 1) * sizeof(int));
    int* cursor = (int*)carve((size_t)N * sizeof(int));
    float* dinv = (float*)carve((size_t)N * sizeof(float));
    int* order = (int*)carve((size_t)Nord * sizeof(int));
    int* col = (int*)carve((size_t)(E + N) * sizeof(int));   // self-loops included
    int* blkT = (int*)carve((size_t)4 * gN * sizeof(int));
    int* blkBase = (int*)carve((size_t)4 * gN * sizeof(int));
    int* partials = (int*)carve((size_t)nb * sizeof(int));
    (void)ws_size;
    (void)n_in;
    (void)out_size;

    k_zero<<<gA, NT, 0, stream>>>(cnt, order, N);
    k_hist_edge<<<gE, NT, 0, stream>>>(edst, cnt, E);
    k_hist_type<<<gN, NT, 0, stream>>>(ntype, blkT, gN, N);
    k_prep<<<384, NT, 0, stream>>>(AW, W1, W2, AWt, W1t, W2t);
    k_scan1<<<nb, NT, 0, stream>>>(cnt, partials, N);
    k_scanmeta<<<1, NT, 0, stream>>>(partials, nb, blkT, blkBase, gN, rowptr, N);
    k_scan3<<<nb, NT, 0, stream>>>(cnt, partials, rowptr, cursor, dinv, col, N);
    k_scatter<<<gN, NT, 0, stream>>>(ntype, blkBase, gN, order, N);
    k_fill<<<gE, NT, 0, stream>>>(esrc, edst, cursor, col, E);

    int bA = gA * 4;                 // 64-row blocks over order space
    int bL = (N + 63) / 64;
    int bG = (N + 3) / 4;            // 1 wave per node

    k_adapt<<<bA, NT, 0, stream>>>(X, ntype, order, AWt, Ab, dinv, A0d);
    // layer 1: S = dinv*sum(A0d); H1d = (S@W1+b1)*dinv  (H1d aliases A0d)
    k_agg<<<bG, NT, 0, stream>>>(A0d, rowptr, col, dinv, Sb, N);
    k_mm<false><<<bL, NT, 0, stream>>>(Sb, W1t, b1, dinv, (void*)A0d, N);
    // layer 2: S = dinv*sum(H1d); out = S@W2 + b2  (f32)
    k_agg<<<bG, NT, 0, stream>>>(A0d, rowptr, col, dinv, Sb, N);
    k_mm<true><<<bL, NT, 0, stream>>>(Sb, W2t, b2, dinv, (void*)out, N);
}

// Round 11
// 241.218 us; speedup vs baseline: 1.1182x; 1.1036x over previous
//
#include <hip/hip_runtime.h>
#include <hip/hip_bf16.h>
#include <cmath>

#define NT 256
#define HID 128

typedef __attribute__((ext_vector_type(8))) short short8v;   // 8 bf16 = 4 VGPR
typedef __attribute__((ext_vector_type(4))) float f32x4;

__device__ __forceinline__ unsigned short f2bf(float f) {
    __hip_bfloat16 h(f);
    return __builtin_bit_cast(unsigned short, h);
}
__device__ __forceinline__ float bf_lo(unsigned int u) { return __uint_as_float(u << 16); }
__device__ __forceinline__ float bf_hi(unsigned int u) { return __uint_as_float(u & 0xffff0000u); }

// cheap round-half-up bf16 pack (inputs finite)
__device__ __forceinline__ unsigned pk(float lo, float hi) {
    unsigned ul = __float_as_uint(lo), uh = __float_as_uint(hi);
    return ((ul + 0x8000u) >> 16) | ((uh + 0x8000u) & 0xffff0000u);
}
__device__ __forceinline__ unsigned short bf1(float v) {
    return (unsigned short)((__float_as_uint(v) + 0x8000u) >> 16);
}

__device__ __forceinline__ float fast_tanh(float x) {
    float cx = fminf(fmaxf(x, -15.f), 15.f);
    float e = __expf(2.f * cx);
    return (e - 1.f) / (e + 1.f);
}

#define MFMA16(a, b, c) __builtin_amdgcn_mfma_f32_16x16x32_bf16(a, b, c, 0, 0, 0)

// ---------------- setup kernels ----------------

// cnt init = 1: self-loop is part of the CSR row
__global__ void k_zero(int* __restrict__ cnt, int* __restrict__ order, int N) {
    int i = blockIdx.x * blockDim.x + threadIdx.x;
    order[i] = -1;
    if (i < N) cnt[i] = 1;
}

__global__ void k_hist_edge(const int* __restrict__ dst, int* __restrict__ cnt, int E) {
    int e = blockIdx.x * blockDim.x + threadIdx.x;
    if (e < E) atomicAdd(&cnt[dst[e]], 1);
}

// per-block type histogram -> blkT[t][b]  (no global atomics)
__global__ void k_hist_type(const int* __restrict__ type, int* __restrict__ blkT,
                            int nb2, int N) {
    __shared__ int h[4];
    int tid = threadIdx.x;
    if (tid < 4) h[tid] = 0;
    __syncthreads();
    int i = blockIdx.x * NT + tid;
    int t = (i < N) ? type[i] : -1;
    int lane = tid & 63;
    #pragma unroll
    for (int tt = 0; tt < 4; ++tt) {
        unsigned long long m = __ballot(t == tt);
        if (lane == 0 && m) atomicAdd(&h[tt], __popcll(m));   // LDS atomic only
    }
    __syncthreads();
    if (tid < 4) blkT[tid * nb2 + blockIdx.x] = h[tid];
}

// block-sum of 1024 cnt entries -> partials[block]
__global__ void k_scan1(const int* __restrict__ cnt, int* __restrict__ partials, int N) {
    __shared__ int sdata[NT];
    int base = blockIdx.x * 1024;
    int tid = threadIdx.x;
    int s = 0;
    #pragma unroll
    for (int k = 0; k < 4; ++k) {
        int idx = base + tid * 4 + k;
        if (idx < N) s += cnt[idx];
    }
    sdata[tid] = s;
    __syncthreads();
    for (int off = NT / 2; off > 0; off >>= 1) {
        if (tid < off) sdata[tid] += sdata[tid + off];
        __syncthreads();
    }
    if (tid == 0) partials[blockIdx.x] = sdata[0];
}

// one block: parallel scan of partials (nb<=512) AND per-type scans of blkT (nb2<=512)
__global__ void k_scanmeta(int* __restrict__ partials, int nb,
                           const int* __restrict__ blkT, int* __restrict__ blkBase,
                           int nb2, int* __restrict__ rowptr, int N) {
    __shared__ int s[NT];
    __shared__ int carry;
    int tid = threadIdx.x;

    int v0 = (tid * 2 < nb) ? partials[tid * 2] : 0;
    int v1 = (tid * 2 + 1 < nb) ? partials[tid * 2 + 1] : 0;
    int ts = v0 + v1;
    s[tid] = ts;
    __syncthreads();
    for (int off = 1; off < NT; off <<= 1) {
        int x = (tid >= off) ? s[tid - off] : 0;
        __syncthreads();
        s[tid] += x;
        __syncthreads();
    }
    int excl = s[tid] - ts;
    if (tid * 2 < nb) partials[tid * 2] = excl;
    if (tid * 2 + 1 < nb) partials[tid * 2 + 1] = excl + v0;
    if (tid == NT - 1) rowptr[N] = s[NT - 1];
    __syncthreads();

    if (tid == 0) carry = 0;
    __syncthreads();
    for (int t = 0; t < 4; ++t) {
        int w0 = (tid * 2 < nb2) ? blkT[t * nb2 + tid * 2] : 0;
        int w1 = (tid * 2 + 1 < nb2) ? blkT[t * nb2 + tid * 2 + 1] : 0;
        int tw = w0 + w1;
        s[tid] = tw;
        __syncthreads();
        for (int off = 1; off < NT; off <<= 1) {
            int x = (tid >= off) ? s[tid - off] : 0;
            __syncthreads();
            s[tid] += x;
            __syncthreads();
        }
        int ex = s[tid] - tw;
        int base = carry;
        if (tid * 2 < nb2) blkBase[t * nb2 + tid * 2] = base + ex;
        if (tid * 2 + 1 < nb2) blkBase[t * nb2 + tid * 2 + 1] = base + ex + w0;
        __syncthreads();
        if (tid == NT - 1) carry = (base + s[NT - 1] + 255) & ~255;
        __syncthreads();
    }
}

// block-local exclusive scan + prefix -> rowptr/cursor/dinv; writes self-loop edge
__global__ void k_scan3(const int* __restrict__ cnt, const int* __restrict__ partials,
                        int* __restrict__ rowptr, int* __restrict__ cursor,
                        float* __restrict__ dinv, int* __restrict__ col, int N) {
    __shared__ int sdata[NT];
    int base = blockIdx.x * 1024;
    int tid = threadIdx.x;
    int a[4];
    int s = 0;
    #pragma unroll
    for (int k = 0; k < 4; ++k) {
        int idx = base + tid * 4 + k;
        a[k] = (idx < N) ? cnt[idx] : 0;
        s += a[k];
    }
    sdata[tid] = s;
    __syncthreads();
    for (int off = 1; off < NT; off <<= 1) {
        int v = (tid >= off) ? sdata[tid - off] : 0;
        __syncthreads();
        sdata[tid] += v;
        __syncthreads();
    }
    int excl = sdata[tid] - s;
    int run = partials[blockIdx.x] + excl;
    #pragma unroll
    for (int k = 0; k < 4; ++k) {
        int idx = base + tid * 4 + k;
        if (idx < N) {
            rowptr[idx] = run;
            col[run] = idx;            // self-loop first in row
            cursor[idx] = run + 1;     // appended edges go after it
            dinv[idx] = rsqrtf((float)a[k]);   // cnt includes self
            run += a[k];
        }
    }
}

// deterministic, atomic-free type-bucketing scatter
__global__ void k_scatter(const int* __restrict__ type, const int* __restrict__ blkBase,
                          int nb2, int* __restrict__ order, int N) {
    __shared__ int wcnt[4][4];   // [wave][type]
    int tid = threadIdx.x, lane = tid & 63, w = tid >> 6;
    int i = blockIdx.x * NT + tid;
    int t = (i < N) ? type[i] : -1;
    unsigned long long below = (1ull << lane) - 1ull;
    unsigned long long mym = 0;
    #pragma unroll
    for (int tt = 0; tt < 4; ++tt) {
        unsigned long long m = __ballot(t == tt);
        if (lane == 0) wcnt[w][tt] = __popcll(m);
        if (t == tt) mym = m;
    }
    __syncthreads();
    if (t >= 0) {
        int off = 0;
        #pragma unroll
        for (int w2 = 0; w2 < 4; ++w2)
            if (w2 < w) off += wcnt[w2][t];
        int pos = blkBase[t * nb2 + blockIdx.x] + off + __popcll(mym & below);
        order[pos] = i;
    }
}

__global__ void k_fill(const int* __restrict__ src, const int* __restrict__ dst,
                       int* __restrict__ cursor, int* __restrict__ col, int E) {
    int e = blockIdx.x * blockDim.x + threadIdx.x;
    if (e < E) {
        int p = atomicAdd(&cursor[dst[e]], 1);
        col[p] = src[e];
    }
}

// convert + transpose weights to bf16: Wt[col][k] = W[k][col]
__global__ void k_prep(const float* __restrict__ AW, const float* __restrict__ W1,
                       const float* __restrict__ W2, unsigned short* __restrict__ AWt,
                       unsigned short* __restrict__ W1t, unsigned short* __restrict__ W2t) {
    int i = blockIdx.x * NT + threadIdx.x;
    if (i < 65536) {
        int t = i >> 14, rem = i & 16383, c = rem >> 7, k = rem & 127;
        AWt[i] = f2bf(AW[t * 16384 + k * 128 + c]);
    } else if (i < 81920) {
        int j = i - 65536, c = j >> 7, k = j & 127;
        W1t[j] = f2bf(W1[k * 128 + c]);
    } else if (i < 98304) {
        int j = i - 81920, c = j >> 7, k = j & 127;
        W2t[j] = f2bf(W2[k * 128 + c]);
    }
}

// ---------------- main kernels ----------------
// mfma_f32_16x16x32_bf16 (m89 layouts): A lane: A[lane&15][8*(lane>>4)+j];
// B lane: B[8*(lane>>4)+j][lane&15]; D: col=lane&15, row=4*(lane>>4)+reg.

// A0d[n] = bf16( tanh(X[n]@AW[t] + Ab[t]) * dinv[n] ); 64-row blocks, W staged in LDS.
__global__ __launch_bounds__(NT) void k_adapt(const float* __restrict__ X,
                                              const int* __restrict__ type,
                                              const int* __restrict__ order,
                                              const unsigned short* __restrict__ AWt,
                                              const float* __restrict__ Ab,
                                              const float* __restrict__ dinv,
                                              unsigned short* __restrict__ A0d) {
    __shared__ unsigned short lds[24576];   // 48 KB: 32 KB W + 16 KB tile
    char* ldsb = (char*)lds;
    char* Tb = ldsb + 32768;
    const int i0 = blockIdx.x * 64;
    int n0 = order[i0];
    if (n0 < 0) return;                     // all-padding block
    const int tid = threadIdx.x;
    const int lane = tid & 63;
    const int w = tid >> 6;
    const int r = lane & 15, g = lane >> 4;
    const int t = __builtin_amdgcn_readfirstlane(type[n0]);
    const unsigned short* Wt = AWt + t * 16384;

    {   // stage W -> LDS (swizzled)
        int row = tid >> 1, half = tid & 1;
        const uint4* src = (const uint4*)(Wt + row * 128 + half * 64);
        #pragma unroll
        for (int j = 0; j < 8; ++j) {
            int gr = half * 8 + j;
            *(uint4*)(ldsb + row * 256 + ((gr ^ (row & 15)) << 4)) = src[j];
        }
    }

    int oid = order[i0 + w * 16 + r];
    float dvl = (oid >= 0) ? dinv[oid] : 0.f;

    float4 xv[8];
    if (oid >= 0) {
        const float4* xp = (const float4*)(X + (size_t)oid * 128);
        #pragma unroll
        for (int s = 0; s < 4; ++s) {
            xv[2 * s] = xp[s * 8 + g * 2];
            xv[2 * s + 1] = xp[s * 8 + g * 2 + 1];
        }
    } else {
        #pragma unroll
        for (int k = 0; k < 8; ++k) xv[k] = float4{0.f, 0.f, 0.f, 0.f};
    }

    float bcol[8];
    #pragma unroll
    for (int c = 0; c < 8; ++c) bcol[c] = Ab[t * 128 + c * 16 + r];

    f32x4 acc[8];
    #pragma unroll
    for (int c = 0; c < 8; ++c) { acc[c][0] = 0.f; acc[c][1] = 0.f; acc[c][2] = 0.f; acc[c][3] = 0.f; }

    __syncthreads();   // W ready

    #pragma unroll
    for (int s = 0; s < 4; ++s) {
        union { short8v s8; unsigned u[4]; } a;
        a.u[0] = pk(xv[2 * s].x, xv[2 * s].y);
        a.u[1] = pk(xv[2 * s].z, xv[2 * s].w);
        a.u[2] = pk(xv[2 * s + 1].x, xv[2 * s + 1].y);
        a.u[3] = pk(xv[2 * s + 1].z, xv[2 * s + 1].w);
        int slot = s * 4 + g;
        #pragma unroll
        for (int c = 0; c < 8; ++c) {
            int wr = 16 * c + r;
            short8v b = *(const short8v*)(ldsb + wr * 256 + ((slot ^ (wr & 15)) << 4));
            acc[c] = MFMA16(a.s8, b, acc[c]);
        }
    }

    float dn[4];
    #pragma unroll
    for (int q = 0; q < 4; ++q) dn[q] = __shfl(dvl, 4 * g + q);
    #pragma unroll
    for (int c = 0; c < 8; ++c) {
        #pragma unroll
        for (int q = 0; q < 4; ++q) {
            int row = w * 16 + 4 * g + q;
            int cb = (c * 16 + r) * 2;
            float v = fast_tanh(acc[c][q] + bcol[c]) * dn[q];
            *(unsigned short*)(Tb + row * 256 + (((cb >> 4) ^ (row & 15)) << 4) + (cb & 15)) = bf1(v);
        }
    }
    // stores: wave-local rows
    int row = tid >> 2;
    int d = order[i0 + row];
    if (d >= 0) {
        unsigned short* dst = A0d + (size_t)d * 128;
        #pragma unroll
        for (int k = 0; k < 4; ++k) {
            int gr = (tid & 3) * 4 + k;
            uint4 v = *(const uint4*)(Tb + row * 256 + ((gr ^ (row & 15)) << 4));
            *(uint4*)(dst + gr * 8) = v;
        }
    }
}

// Standalone gather-sum: S[d] = bf16( dinv[d] * sum_{e in row d} Yin[col[e]] )
// (self-loop is in the CSR). 1 wave per node, 8 row-gathers in flight.
__global__ __launch_bounds__(NT) void k_agg(const unsigned short* __restrict__ Yin,
                                            const int* __restrict__ rowptr,
                                            const int* __restrict__ col,
                                            const float* __restrict__ dinv,
                                            unsigned short* __restrict__ Sout, int N) {
    int gw = (int)((blockIdx.x * (unsigned)blockDim.x + threadIdx.x) >> 6);
    int lane = threadIdx.x & 63;
    if (gw >= N) return;
    const unsigned* Yw = (const unsigned*)Yin;
    int beg = rowptr[gw], end = rowptr[gw + 1];
    float ax = 0.f, ay = 0.f;
    for (int base = beg; base < end; base += 64) {
        int m = end - base;
        if (m > 64) m = 64;
        int ce = (lane < m) ? col[base + lane] : col[beg];   // pad = self row
        for (int k = 0; k < m; k += 8) {
            unsigned v[8];
            #pragma unroll
            for (int j = 0; j < 8; ++j) {
                int idx = (k + j < m) ? k + j : 0;
                int s = __shfl(ce, idx);
                v[j] = Yw[(size_t)s * 64 + lane];
            }
            #pragma unroll
            for (int j = 0; j < 8; ++j) {
                float wj = (k + j < m) ? 1.f : 0.f;
                ax = fmaf(wj, bf_lo(v[j]), ax);
                ay = fmaf(wj, bf_hi(v[j]), ay);
            }
        }
    }
    float dn = dinv[gw];
    ((unsigned*)Sout)[(size_t)gw * 64 + lane] = pk(ax * dn, ay * dn);
}

// Persistent GEMM with wave-stationary B (W lives in 128 VGPRs; loaded once per wave).
// Grid-strides over 16-row tiles. No barriers; bf16 path uses per-wave 4KB LDS transpose.
// OUTF32=false: out_bf16[d] = (S@W + bias)*dinv[d];  OUTF32=true: out_f32[d] = S@W + bias.
template <bool OUTF32>
__global__ __launch_bounds__(NT, 1) void k_mm(const unsigned short* __restrict__ Ain,
                                              const unsigned short* __restrict__ Wt,
                                              const float* __restrict__ bias,
                                              const float* __restrict__ dinv,
                                              void* __restrict__ outp, int N, int nt) {
    __shared__ unsigned short lds[8192];    // 16 KB: 4 KB per wave (bf16 path only)
    const int tid = threadIdx.x;
    const int lane = tid & 63;
    const int w = tid >> 6;
    const int r = lane & 15, g = lane >> 4;
    char* Tb = (char*)lds + w * 4096;

    // stationary B fragments: whole 32KB W in VGPRs (batched loads, L2-hot)
    short8v B[32];
    #pragma unroll
    for (int s = 0; s < 4; ++s)
        #pragma unroll
        for (int c = 0; c < 8; ++c)
            B[s * 8 + c] = *(const short8v*)(Wt + (size_t)(16 * c + r) * 128 + (s * 4 + g) * 8);

    float bcol[8];
    #pragma unroll
    for (int c = 0; c < 8; ++c) bcol[c] = bias[c * 16 + r];

    for (int t = blockIdx.x * 4 + w; t < nt; t += gridDim.x * 4) {
        const int nbase = t * 16;
        int n = nbase + r;
        if (n >= N) n = N - 1;              // clamp (stores guarded)
        const unsigned short* arow = Ain + (size_t)n * 128;

        f32x4 acc[8];
        #pragma unroll
        for (int c = 0; c < 8; ++c) { acc[c][0] = 0.f; acc[c][1] = 0.f; acc[c][2] = 0.f; acc[c][3] = 0.f; }

        #pragma unroll
        for (int s = 0; s < 4; ++s) {
            short8v a = *(const short8v*)(arow + s * 32 + g * 8);   // 64B segments, coalesced
            #pragma unroll
            for (int c = 0; c < 8; ++c)
                acc[c] = MFMA16(a, B[s * 8 + c], acc[c]);
        }

        if (OUTF32) {
            #pragma unroll
            for (int c = 0; c < 8; ++c) {
                #pragma unroll
                for (int q = 0; q < 4; ++q) {
                    int d = nbase + 4 * g + q;
                    if (d < N)
                        ((float*)outp)[(size_t)d * 128 + c * 16 + r] = acc[c][q] + bcol[c];
                }
            }
        } else {
            float dnq[4];
            #pragma unroll
            for (int q = 0; q < 4; ++q) {
                int dd = nbase + 4 * g + q;
                dnq[q] = (dd < N) ? dinv[dd] : 0.f;
            }
            // per-wave LDS transpose (local rows 0..15); wave-local -> no barrier
            #pragma unroll
            for (int c = 0; c < 8; ++c) {
                #pragma unroll
                for (int q = 0; q < 4; ++q) {
                    int j = 4 * g + q;
                    int cb = (c * 16 + r) * 2;
                    float v = (acc[c][q] + bcol[c]) * dnq[q];
                    *(unsigned short*)(Tb + j * 256 + (((cb >> 4) ^ j) << 4) + (cb & 15)) = bf1(v);
                }
            }
            int j = lane >> 2;              // local row 0..15
            int d = nbase + j;
            if (d < N) {
                unsigned short* dst = (unsigned short*)outp + (size_t)d * 128;
                #pragma unroll
                for (int k = 0; k < 4; ++k) {
                    int gr = (lane & 3) * 4 + k;
                    uint4 v = *(const uint4*)(Tb + j * 256 + ((gr ^ j) << 4));
                    *(uint4*)(dst + gr * 8) = v;
                }
            }
        }
    }
}

// ---------------- launch ----------------

extern "C" void kernel_launch(void* const* d_in, const int* in_sizes, int n_in,
                              void* d_out, int out_size, void* d_ws, size_t ws_size,
                              hipStream_t stream) {
    const float* X = (const float*)d_in[0];
    const int* ntype = (const int*)d_in[1];
    const int* eidx = (const int*)d_in[3];
    const float* AW = (const float*)d_in[5];
    const float* Ab = (const float*)d_in[6];
    const float* W1 = (const float*)d_in[7];
    const float* b1 = (const float*)d_in[8];
    const float* W2 = (const float*)d_in[9];
    const float* b2 = (const float*)d_in[10];

    int N = in_sizes[0] / HID;
    int E = in_sizes[3] / 2;
    const int* esrc = eidx;
    const int* edst = eidx + E;
    float* out = (float*)d_out;

    int gN = (N + NT - 1) / NT;      // also nb2 (<=512)
    int gE = (E + NT - 1) / NT;
    int gA = gN + 4;                 // padded bucket blocks (256-aligned starts)
    int Nord = gA * NT;
    int nb = (N + 1023) / 1024;      // <= 512

    char* ws = (char*)d_ws;
    size_t off = 0;
    auto carve = [&](size_t bytes) -> void* {
        void* p = ws + off;
        off += (bytes + 255) & ~(size_t)255;
        return p;
    };
    unsigned short* A0d = (unsigned short*)carve((size_t)N * HID * 2);  // adapt out / mm1 out (aliased)
    unsigned short* Sb = (unsigned short*)carve((size_t)N * HID * 2);   // agg out
    unsigned short* AWt = (unsigned short*)carve(4 * 16384 * 2);
    unsigned short* W1t = (unsigned short*)carve(16384 * 2);
    unsigned short* W2t = (unsigned short*)carve(16384 * 2);
    int* cnt = (int*)carve((size_t)N * sizeof(int));
    int* rowptr = (int*)carve((size_t)(N + 1) * sizeof(int));
    int* cursor = (int*)carve((size_t)N * sizeof(int));
    float* dinv = (float*)carve((size_t)N * sizeof(float));
    int* order = (int*)carve((size_t)Nord * sizeof(int));
    int* col = (int*)carve((size_t)(E + N) * sizeof(int));   // self-loops included
    int* blkT = (int*)carve((size_t)4 * gN * sizeof(int));
    int* blkBase = (int*)carve((size_t)4 * gN * sizeof(int));
    int* partials = (int*)carve((size_t)nb * sizeof(int));
    (void)ws_size;
    (void)n_in;
    (void)out_size;

    k_zero<<<gA, NT, 0, stream>>>(cnt, order, N);
    k_hist_edge<<<gE, NT, 0, stream>>>(edst, cnt, E);
    k_hist_type<<<gN, NT, 0, stream>>>(ntype, blkT, gN, N);
    k_prep<<<384, NT, 0, stream>>>(AW, W1, W2, AWt, W1t, W2t);
    k_scan1<<<nb, NT, 0, stream>>>(cnt, partials, N);
    k_scanmeta<<<1, NT, 0, stream>>>(partials, nb, blkT, blkBase, gN, rowptr, N);
    k_scan3<<<nb, NT, 0, stream>>>(cnt, partials, rowptr, cursor, dinv, col, N);
    k_scatter<<<gN, NT, 0, stream>>>(ntype, blkBase, gN, order, N);
    k_fill<<<gE, NT, 0, stream>>>(esrc, edst, cursor, col, E);

    int bA = gA * 4;                 // 64-row blocks over order space
    int bG = (N + 3) / 4;            // 1 wave per node
    int nt = (N + 15) / 16;          // 16-row tiles for k_mm
    int bM = (nt + 3) / 4;
    if (bM > 1024) bM = 1024;        // persistent grid

    k_adapt<<<bA, NT, 0, stream>>>(X, ntype, order, AWt, Ab, dinv, A0d);
    // layer 1: S = dinv*sum(A0d); H1d = (S@W1+b1)*dinv  (H1d aliases A0d)
    k_agg<<<bG, NT, 0, stream>>>(A0d, rowptr, col, dinv, Sb, N);
    k_mm<false><<<bM, NT, 0, stream>>>(Sb, W1t, b1, dinv, (void*)A0d, N, nt);
    // layer 2: S = dinv*sum(H1d); out = S@W2 + b2  (f32)
    k_agg<<<bG, NT, 0, stream>>>(A0d, rowptr, col, dinv, Sb, N);
    k_mm<true><<<bM, NT, 0, stream>>>(Sb, W2t, b2, dinv, (void*)out, N, nt);
}